// Round 9
// baseline (97.213 us; speedup 1.0000x reference)
//
#include <hip/hip_runtime.h>

// Per-element MLP 1->32->(32x32)x9->1, leaky relu, v_mfma_f32_16x16x32_f16.
// R14 = R12's schedule with helper functions MANUALLY INLINED. R12/R13 both
// died on "container failed twice" (no compile/numeric verdict). H-infra vs
// H-kernel is unresolved; the one unusual pattern vs every kernel that DID
// bench (R5-R11) was helpers taking ext-vector-array params inside the
// rolled loop (inliner/regalloc stressor). Flattening tests the same theory
// under both hypotheses.
// Theory (unchanged from R12): R9-R11 flat at ~36us steady because per-layer
// mfma->VALU acc-read latency (~150cyc) dominates. Fix: 16x16x32 shape
// (4-reg accs; layout verified end-to-end in R10) + NCHAIN=6 in 3 STAGGERED
// groups of 2:  MFMA(g0) MFMA(g1) epi(g0) MFMA(g2) epi(g1) epi(g2)
// -> per-layer wave-busy ~80%, 2 waves/SIMD saturate the VALU pipe.
// Regs: f-state 48 + 2 acc-groups 64 + rotated wA/bc 32 + io 12 + x 12 +
// misc ~16 = ~184 peak, inside the (256,2)=256 budget proven spill-free
// (R5 at ~192). LDS pre-permuted weights + rolled layer loop (R9 fix).
#define NLAYERS 9
#define HID 32
#define SLOPE 0.01f

typedef _Float16 v2h __attribute__((ext_vector_type(2)));
typedef _Float16 v8h __attribute__((ext_vector_type(8)));
typedef float v4f __attribute__((ext_vector_type(4)));

#define NCHAIN 6

union U8 { v8h v; v2h p[4]; };          // B-operand fragment (8 f16 = 4 VGPRs)

__device__ __forceinline__ v2h pk_cvt(float a, float b) {
    return __builtin_bit_cast(v2h, __builtin_amdgcn_cvt_pkrtz(a, b));
}
__device__ __forceinline__ v2h leaky2(v2h t, v2h s) {
    return __builtin_elementwise_max(t, t * s);
}
// k-slot (group g = lane>>4, elem j) -> logical hidden unit; derived from the
// verified 16x16 C/D layout so epilogue pk pairs feed the next B directly
// (validated numerically in R10).
__device__ __forceinline__ int umap(int g, int j) {
    return 4 * g + (j & 3) + 16 * (j >> 2);
}

__global__ __launch_bounds__(256, 2) void mlp_mfma_kernel(
    const float* __restrict__ x,
    const float* __restrict__ W_in,   // [1,32]
    const float* __restrict__ b_in,   // [32]
    const float* __restrict__ W_hid,  // [9,32,32]  W[l][k_in][n_out]
    const float* __restrict__ b_hid,  // [9,32]
    const float* __restrict__ W_out,  // [32,1]
    const float* __restrict__ b_out,  // [1]
    float* __restrict__ out, int N)
{
    // A-operand fragments, pre-permuted: lane ln=(i | g<<4) of tile t reads
    // 16B contiguous = W[umap(g,j)][16t+i], j=0..7. 64x16B = conflict-free.
    __shared__ __align__(16) _Float16 wA_sh[NLAYERS][2][64][8];  // 18 KiB
    // f32 bias in 16x16 C layout: tile t, entry 4g+r <- b_hid[16t+4g+r]
    __shared__ __align__(64) float bc_sh[NLAYERS][2][16];        // 1.1 KiB

    const int tid = threadIdx.x;
    for (int t = tid; t < NLAYERS * 2 * 64; t += blockDim.x) {
        int l = t >> 7, r = t & 127, tt = (r >> 6) & 1, ln = r & 63;
        int i = ln & 15, gg = ln >> 4;
        const float* Wl = W_hid + l * HID * HID;
        v8h w;
#pragma unroll
        for (int j = 0; j < 8; ++j)
            w[j] = (_Float16)Wl[umap(gg, j) * HID + 16 * tt + i];
        *(v8h*)&wA_sh[l][tt][ln][0] = w;
    }
    for (int t = tid; t < NLAYERS * HID; t += blockDim.x)
        ((float*)bc_sh)[t] = b_hid[t];   // flat layout matches b_hid exactly
    __syncthreads();

    const int lane = tid & 63;
    const int g    = lane >> 4;     // k-group / C-row group
    const int col  = lane & 15;     // batch column within 16-wide half

    // ---- register-resident io-layer fragments (12 VGPRs) ----
    v2h win2[4], bin2[4], wout2[4];
#pragma unroll
    for (int jj = 0; jj < 4; ++jj) {
        int u0 = umap(g, 2 * jj), u1 = umap(g, 2 * jj + 1);  // u1 == u0+1
        win2[jj]  = v2h{(_Float16)W_in[u0],  (_Float16)W_in[u1]};
        bin2[jj]  = v2h{(_Float16)b_in[u0],  (_Float16)b_in[u1]};
        wout2[jj] = v2h{(_Float16)W_out[u0], (_Float16)W_out[u1]};
    }
    const float bo = b_out[0];
    const v2h slope2 = v2h{(_Float16)SLOPE, (_Float16)SLOPE};

    const int nwaves = (gridDim.x * blockDim.x) >> 6;
    const int wid    = (blockIdx.x * blockDim.x + tid) >> 6;
    const int niter  = (N + NCHAIN * 32 - 1) / (NCHAIN * 32);

    // ---- x prefetch for first iteration, packed f16 (2 cols/lane/chain) ----
    v2h xc2[NCHAIN];
#pragma unroll
    for (int c = 0; c < NCHAIN; ++c) xc2[c] = v2h{(_Float16)0.f, (_Float16)0.f};
    if (wid < niter) {
#pragma unroll
        for (int c = 0; c < NCHAIN; ++c) {
            int i0 = wid * (NCHAIN * 32) + c * 32 + col;
            int i1 = i0 + 16;
            float a = (i0 < N) ? x[i0] : 0.0f;
            float b = (i1 < N) ? x[i1] : 0.0f;
            xc2[c] = pk_cvt(a, b);
        }
    }

    for (int it = wid; it < niter; it += nwaves) {
        // prefetch next iteration's x (hides HBM latency under compute)
        v2h xn2[NCHAIN];
#pragma unroll
        for (int c = 0; c < NCHAIN; ++c) xn2[c] = v2h{(_Float16)0.f, (_Float16)0.f};
        {
            int nit = it + nwaves;
            if (nit < niter) {
#pragma unroll
                for (int c = 0; c < NCHAIN; ++c) {
                    int i0 = nit * (NCHAIN * 32) + c * 32 + col;
                    int i1 = i0 + 16;
                    float a = (i0 < N) ? x[i0] : 0.0f;
                    float b = (i1 < N) ? x[i1] : 0.0f;
                    xn2[c] = pk_cvt(a, b);
                }
            }
        }

        // ---- input layer: build B fragments for all chains/halves ----
        U8 f[NCHAIN][2];
#pragma unroll
        for (int c = 0; c < NCHAIN; ++c)
#pragma unroll
            for (int nh = 0; nh < 2; ++nh) {
                _Float16 xh = xc2[c][nh];
                v2h x2 = v2h{xh, xh};
#pragma unroll
                for (int jj = 0; jj < 4; ++jj)
                    f[c][nh].p[jj] = leaky2(x2 * win2[jj] + bin2[jj], slope2);
            }

        // ---- 9 hidden layers: REAL loop (no unroll; spill lesson R6/R7),
        // weights/bias rotated; 3 acc-groups STAGGERED (all inline) so MFMA
        // issue of group n+1 covers the ~150cyc acc-read latency of group n.
        v8h wA0 = *(const v8h*)&wA_sh[0][0][lane][0];
        v8h wA1 = *(const v8h*)&wA_sh[0][1][lane][0];
        v4f bc0 = *(const v4f*)&bc_sh[0][0][4 * g];
        v4f bc1 = *(const v4f*)&bc_sh[0][1][4 * g];
#pragma unroll 1
        for (int l = 0; l < NLAYERS; ++l) {
            const int lnx = (l + 1 < NLAYERS) ? l + 1 : l;
            v8h wA0n = *(const v8h*)&wA_sh[lnx][0][lane][0];
            v8h wA1n = *(const v8h*)&wA_sh[lnx][1][lane][0];
            v4f bc0n = *(const v4f*)&bc_sh[lnx][0][4 * g];
            v4f bc1n = *(const v4f*)&bc_sh[lnx][1][4 * g];

            v4f A0[2][4], A1[2][4], A2[2][4];
            // MFMA group 0 (chains 0,1)
#pragma unroll
            for (int q = 0; q < 2; ++q) {
                A0[q][0] = __builtin_amdgcn_mfma_f32_16x16x32_f16(wA0, f[q][0].v, bc0, 0, 0, 0);
                A0[q][1] = __builtin_amdgcn_mfma_f32_16x16x32_f16(wA0, f[q][1].v, bc0, 0, 0, 0);
                A0[q][2] = __builtin_amdgcn_mfma_f32_16x16x32_f16(wA1, f[q][0].v, bc1, 0, 0, 0);
                A0[q][3] = __builtin_amdgcn_mfma_f32_16x16x32_f16(wA1, f[q][1].v, bc1, 0, 0, 0);
            }
            // MFMA group 1 (chains 2,3)
#pragma unroll
            for (int q = 0; q < 2; ++q) {
                A1[q][0] = __builtin_amdgcn_mfma_f32_16x16x32_f16(wA0, f[2 + q][0].v, bc0, 0, 0, 0);
                A1[q][1] = __builtin_amdgcn_mfma_f32_16x16x32_f16(wA0, f[2 + q][1].v, bc0, 0, 0, 0);
                A1[q][2] = __builtin_amdgcn_mfma_f32_16x16x32_f16(wA1, f[2 + q][0].v, bc1, 0, 0, 0);
                A1[q][3] = __builtin_amdgcn_mfma_f32_16x16x32_f16(wA1, f[2 + q][1].v, bc1, 0, 0, 0);
            }
            // epi group 0 (covered by group 1's MFMA latency)
#pragma unroll
            for (int q = 0; q < 2; ++q) {
                f[q][0].p[0] = leaky2(pk_cvt(A0[q][0][0], A0[q][0][1]), slope2);
                f[q][0].p[1] = leaky2(pk_cvt(A0[q][0][2], A0[q][0][3]), slope2);
                f[q][0].p[2] = leaky2(pk_cvt(A0[q][2][0], A0[q][2][1]), slope2);
                f[q][0].p[3] = leaky2(pk_cvt(A0[q][2][2], A0[q][2][3]), slope2);
                f[q][1].p[0] = leaky2(pk_cvt(A0[q][1][0], A0[q][1][1]), slope2);
                f[q][1].p[1] = leaky2(pk_cvt(A0[q][1][2], A0[q][1][3]), slope2);
                f[q][1].p[2] = leaky2(pk_cvt(A0[q][3][0], A0[q][3][1]), slope2);
                f[q][1].p[3] = leaky2(pk_cvt(A0[q][3][2], A0[q][3][3]), slope2);
            }
            // MFMA group 2 (chains 4,5)
#pragma unroll
            for (int q = 0; q < 2; ++q) {
                A2[q][0] = __builtin_amdgcn_mfma_f32_16x16x32_f16(wA0, f[4 + q][0].v, bc0, 0, 0, 0);
                A2[q][1] = __builtin_amdgcn_mfma_f32_16x16x32_f16(wA0, f[4 + q][1].v, bc0, 0, 0, 0);
                A2[q][2] = __builtin_amdgcn_mfma_f32_16x16x32_f16(wA1, f[4 + q][0].v, bc1, 0, 0, 0);
                A2[q][3] = __builtin_amdgcn_mfma_f32_16x16x32_f16(wA1, f[4 + q][1].v, bc1, 0, 0, 0);
            }
            // epi group 1 (covered by group 2's MFMA latency)
#pragma unroll
            for (int q = 0; q < 2; ++q) {
                f[2 + q][0].p[0] = leaky2(pk_cvt(A1[q][0][0], A1[q][0][1]), slope2);
                f[2 + q][0].p[1] = leaky2(pk_cvt(A1[q][0][2], A1[q][0][3]), slope2);
                f[2 + q][0].p[2] = leaky2(pk_cvt(A1[q][2][0], A1[q][2][1]), slope2);
                f[2 + q][0].p[3] = leaky2(pk_cvt(A1[q][2][2], A1[q][2][3]), slope2);
                f[2 + q][1].p[0] = leaky2(pk_cvt(A1[q][1][0], A1[q][1][1]), slope2);
                f[2 + q][1].p[1] = leaky2(pk_cvt(A1[q][1][2], A1[q][1][3]), slope2);
                f[2 + q][1].p[2] = leaky2(pk_cvt(A1[q][3][0], A1[q][3][1]), slope2);
                f[2 + q][1].p[3] = leaky2(pk_cvt(A1[q][3][2], A1[q][3][3]), slope2);
            }
            // epi group 2
#pragma unroll
            for (int q = 0; q < 2; ++q) {
                f[4 + q][0].p[0] = leaky2(pk_cvt(A2[q][0][0], A2[q][0][1]), slope2);
                f[4 + q][0].p[1] = leaky2(pk_cvt(A2[q][0][2], A2[q][0][3]), slope2);
                f[4 + q][0].p[2] = leaky2(pk_cvt(A2[q][2][0], A2[q][2][1]), slope2);
                f[4 + q][0].p[3] = leaky2(pk_cvt(A2[q][2][2], A2[q][2][3]), slope2);
                f[4 + q][1].p[0] = leaky2(pk_cvt(A2[q][1][0], A2[q][1][1]), slope2);
                f[4 + q][1].p[1] = leaky2(pk_cvt(A2[q][1][2], A2[q][1][3]), slope2);
                f[4 + q][1].p[2] = leaky2(pk_cvt(A2[q][3][0], A2[q][3][1]), slope2);
                f[4 + q][1].p[3] = leaky2(pk_cvt(A2[q][3][2], A2[q][3][3]), slope2);
            }
            // peak acc liveness: 2 groups = 64 VGPRs

            wA0 = wA0n; wA1 = wA1n; bc0 = bc0n; bc1 = bc1n;
        }

        // ---- output layer: fdot2, then 4-group shuffle reduce ----
#pragma unroll
        for (int c = 0; c < NCHAIN; ++c)
#pragma unroll
            for (int nh = 0; nh < 2; ++nh) {
                float p = 0.0f;
#pragma unroll
                for (int jj = 0; jj < 4; ++jj)
                    p = __builtin_amdgcn_fdot2(f[c][nh].p[jj], wout2[jj], p, false);
                p += __shfl_xor(p, 16, 64);
                p += __shfl_xor(p, 32, 64);   // sum over all 4 k-groups
                float o = p + bo;
                int idx = it * (NCHAIN * 32) + c * 32 + 16 * nh + col;
                // 12 (c,nh) combos split 3-per-16-lane-group (coalesced 64B)
                if (((2 * c + nh) & 3) == g && idx < N) out[idx] = o;
            }

#pragma unroll
        for (int c = 0; c < NCHAIN; ++c) xc2[c] = xn2[c];
    }
}

extern "C" void kernel_launch(void* const* d_in, const int* in_sizes, int n_in,
                              void* d_out, int out_size, void* d_ws, size_t ws_size,
                              hipStream_t stream) {
    const float* x     = (const float*)d_in[0];
    const float* W_in  = (const float*)d_in[1];
    const float* b_in  = (const float*)d_in[2];
    const float* W_hid = (const float*)d_in[3];
    const float* b_hid = (const float*)d_in[4];
    const float* W_out = (const float*)d_in[5];
    const float* b_out = (const float*)d_in[6];
    float* out = (float*)d_out;

    int N = in_sizes[0];
    // 512 blocks x 4 waves = 2048 waves = 2 waves/SIMD (256-reg budget,
    // ~184 peak -> spill-free region proven by R5; 19.6 KiB LDS x 2 blocks).
    // niter = ceil(N/192) = 5462 -> 2-3 iterations/wave.
    dim3 block(256);
    dim3 grid(512);
    mlp_mfma_kernel<<<grid, block, 0, stream>>>(x, W_in, b_in, W_hid, b_hid,
                                                W_out, b_out, out, N);
}

// Round 10
// 93.328 us; speedup vs baseline: 1.0416x; 1.0416x over previous
//
#include <hip/hip_runtime.h>

// Per-element MLP 1->32->(32x32)x9->1, leaky relu, v_mfma_f32_16x16x32_f16.
// R15: R14's counters falsified the in-wave-ILP theory: R5/R8/R14 (three
// different ILP structures) all plateau ~42us; MfmaUtil 17%, VALUBusy 39%,
// Occupancy 14.8%, VGPR_Count=88 (!) -> the wave is small and the kernel is
// GRID-pinned at 2 blocks/CU (512 blocks), not register-pinned. The ~80%
// pipe idle is latency that only TLP can cover. Fix: minimize per-wave
// state and maximize waves. NCHAIN=2 (one 2-chain group), NO weight
// rotation (TLP covers the layer-top lgkm wait; -16 regs), rolled layer
// loop, LDS pre-permuted weights. Audit: f 16 + accs 32 + wA/bc 16 + io 12
// + x 4 + misc 12 ~= 92 regs -> 5 waves/SIMD. launch_bounds(256,4) = 128
// cap with 35+ slack (not the R6 spill trap). Grid 1280 = 5 blocks/CU
// (97.6 KiB LDS/CU), 5120 waves, niter 16384 -> 3.2 iters/wave.
#define NLAYERS 9
#define HID 32
#define SLOPE 0.01f

typedef _Float16 v2h __attribute__((ext_vector_type(2)));
typedef _Float16 v8h __attribute__((ext_vector_type(8)));
typedef float v4f __attribute__((ext_vector_type(4)));

#define NCHAIN 2

union U8 { v8h v; v2h p[4]; };          // B-operand fragment (8 f16 = 4 VGPRs)

__device__ __forceinline__ v2h pk_cvt(float a, float b) {
    return __builtin_bit_cast(v2h, __builtin_amdgcn_cvt_pkrtz(a, b));
}
__device__ __forceinline__ v2h leaky2(v2h t, v2h s) {
    return __builtin_elementwise_max(t, t * s);
}
// k-slot (group g = lane>>4, elem j) -> logical hidden unit; derived from the
// verified 16x16 C/D layout so epilogue pk pairs feed the next B directly
// (validated numerically in R10/R14).
__device__ __forceinline__ int umap(int g, int j) {
    return 4 * g + (j & 3) + 16 * (j >> 2);
}

__global__ __launch_bounds__(256, 4) void mlp_mfma_kernel(
    const float* __restrict__ x,
    const float* __restrict__ W_in,   // [1,32]
    const float* __restrict__ b_in,   // [32]
    const float* __restrict__ W_hid,  // [9,32,32]  W[l][k_in][n_out]
    const float* __restrict__ b_hid,  // [9,32]
    const float* __restrict__ W_out,  // [32,1]
    const float* __restrict__ b_out,  // [1]
    float* __restrict__ out, int N)
{
    // A-operand fragments, pre-permuted: lane ln=(i | g<<4) of tile t reads
    // 16B contiguous = W[umap(g,j)][16t+i], j=0..7. 64x16B = conflict-free.
    __shared__ __align__(16) _Float16 wA_sh[NLAYERS][2][64][8];  // 18 KiB
    // f32 bias in 16x16 C layout: tile t, entry 4g+r <- b_hid[16t+4g+r]
    __shared__ __align__(64) float bc_sh[NLAYERS][2][16];        // 1.1 KiB

    const int tid = threadIdx.x;
    for (int t = tid; t < NLAYERS * 2 * 64; t += blockDim.x) {
        int l = t >> 7, r = t & 127, tt = (r >> 6) & 1, ln = r & 63;
        int i = ln & 15, gg = ln >> 4;
        const float* Wl = W_hid + l * HID * HID;
        v8h w;
#pragma unroll
        for (int j = 0; j < 8; ++j)
            w[j] = (_Float16)Wl[umap(gg, j) * HID + 16 * tt + i];
        *(v8h*)&wA_sh[l][tt][ln][0] = w;
    }
    for (int t = tid; t < NLAYERS * HID; t += blockDim.x)
        ((float*)bc_sh)[t] = b_hid[t];   // flat layout matches b_hid exactly
    __syncthreads();

    const int lane = tid & 63;
    const int g    = lane >> 4;     // k-group / C-row group
    const int col  = lane & 15;     // batch column within 16-wide half

    // ---- register-resident io-layer fragments (12 VGPRs) ----
    v2h win2[4], bin2[4], wout2[4];
#pragma unroll
    for (int jj = 0; jj < 4; ++jj) {
        int u0 = umap(g, 2 * jj), u1 = umap(g, 2 * jj + 1);  // u1 == u0+1
        win2[jj]  = v2h{(_Float16)W_in[u0],  (_Float16)W_in[u1]};
        bin2[jj]  = v2h{(_Float16)b_in[u0],  (_Float16)b_in[u1]};
        wout2[jj] = v2h{(_Float16)W_out[u0], (_Float16)W_out[u1]};
    }
    const float bo = b_out[0];
    const v2h slope2 = v2h{(_Float16)SLOPE, (_Float16)SLOPE};

    const int nwaves = (gridDim.x * blockDim.x) >> 6;
    const int wid    = (blockIdx.x * blockDim.x + tid) >> 6;
    const int niter  = (N + NCHAIN * 32 - 1) / (NCHAIN * 32);

    // ---- x prefetch for first iteration, packed f16 (2 cols/lane/chain) ----
    v2h xc2[NCHAIN];
#pragma unroll
    for (int c = 0; c < NCHAIN; ++c) xc2[c] = v2h{(_Float16)0.f, (_Float16)0.f};
    if (wid < niter) {
#pragma unroll
        for (int c = 0; c < NCHAIN; ++c) {
            int i0 = wid * (NCHAIN * 32) + c * 32 + col;
            int i1 = i0 + 16;
            float a = (i0 < N) ? x[i0] : 0.0f;
            float b = (i1 < N) ? x[i1] : 0.0f;
            xc2[c] = pk_cvt(a, b);
        }
    }

    for (int it = wid; it < niter; it += nwaves) {
        // prefetch next iteration's x (hides HBM latency under compute)
        v2h xn2[NCHAIN];
#pragma unroll
        for (int c = 0; c < NCHAIN; ++c) xn2[c] = v2h{(_Float16)0.f, (_Float16)0.f};
        {
            int nit = it + nwaves;
            if (nit < niter) {
#pragma unroll
                for (int c = 0; c < NCHAIN; ++c) {
                    int i0 = nit * (NCHAIN * 32) + c * 32 + col;
                    int i1 = i0 + 16;
                    float a = (i0 < N) ? x[i0] : 0.0f;
                    float b = (i1 < N) ? x[i1] : 0.0f;
                    xn2[c] = pk_cvt(a, b);
                }
            }
        }

        // ---- input layer: build B fragments for both chains/halves ----
        U8 f[NCHAIN][2];
#pragma unroll
        for (int c = 0; c < NCHAIN; ++c)
#pragma unroll
            for (int nh = 0; nh < 2; ++nh) {
                _Float16 xh = xc2[c][nh];
                v2h x2 = v2h{xh, xh};
#pragma unroll
                for (int jj = 0; jj < 4; ++jj)
                    f[c][nh].p[jj] = leaky2(x2 * win2[jj] + bin2[jj], slope2);
            }

        // ---- 9 hidden layers: REAL loop (no unroll; spill lesson R6/R7).
        // No rotation: at 4-5 waves/SIMD the layer-top lgkm wait is covered
        // by other waves (TLP), and the saved 16 regs buy that occupancy.
#pragma unroll 1
        for (int l = 0; l < NLAYERS; ++l) {
            v8h wA0 = *(const v8h*)&wA_sh[l][0][lane][0];   // ds_read_b128
            v8h wA1 = *(const v8h*)&wA_sh[l][1][lane][0];   // ds_read_b128
            v4f bc0 = *(const v4f*)&bc_sh[l][0][4 * g];     // b128 broadcast
            v4f bc1 = *(const v4f*)&bc_sh[l][1][4 * g];

            v4f A0[4], A1[4];
            // chain 0 MFMAs, then chain 1 (independent), then epilogues:
            // chain 1's issue covers part of chain 0's acc-read latency.
            A0[0] = __builtin_amdgcn_mfma_f32_16x16x32_f16(wA0, f[0][0].v, bc0, 0, 0, 0);
            A0[1] = __builtin_amdgcn_mfma_f32_16x16x32_f16(wA0, f[0][1].v, bc0, 0, 0, 0);
            A0[2] = __builtin_amdgcn_mfma_f32_16x16x32_f16(wA1, f[0][0].v, bc1, 0, 0, 0);
            A0[3] = __builtin_amdgcn_mfma_f32_16x16x32_f16(wA1, f[0][1].v, bc1, 0, 0, 0);
            A1[0] = __builtin_amdgcn_mfma_f32_16x16x32_f16(wA0, f[1][0].v, bc0, 0, 0, 0);
            A1[1] = __builtin_amdgcn_mfma_f32_16x16x32_f16(wA0, f[1][1].v, bc0, 0, 0, 0);
            A1[2] = __builtin_amdgcn_mfma_f32_16x16x32_f16(wA1, f[1][0].v, bc1, 0, 0, 0);
            A1[3] = __builtin_amdgcn_mfma_f32_16x16x32_f16(wA1, f[1][1].v, bc1, 0, 0, 0);

            f[0][0].p[0] = leaky2(pk_cvt(A0[0][0], A0[0][1]), slope2);
            f[0][0].p[1] = leaky2(pk_cvt(A0[0][2], A0[0][3]), slope2);
            f[0][0].p[2] = leaky2(pk_cvt(A0[2][0], A0[2][1]), slope2);
            f[0][0].p[3] = leaky2(pk_cvt(A0[2][2], A0[2][3]), slope2);
            f[0][1].p[0] = leaky2(pk_cvt(A0[1][0], A0[1][1]), slope2);
            f[0][1].p[1] = leaky2(pk_cvt(A0[1][2], A0[1][3]), slope2);
            f[0][1].p[2] = leaky2(pk_cvt(A0[3][0], A0[3][1]), slope2);
            f[0][1].p[3] = leaky2(pk_cvt(A0[3][2], A0[3][3]), slope2);
            f[1][0].p[0] = leaky2(pk_cvt(A1[0][0], A1[0][1]), slope2);
            f[1][0].p[1] = leaky2(pk_cvt(A1[0][2], A1[0][3]), slope2);
            f[1][0].p[2] = leaky2(pk_cvt(A1[2][0], A1[2][1]), slope2);
            f[1][0].p[3] = leaky2(pk_cvt(A1[2][2], A1[2][3]), slope2);
            f[1][1].p[0] = leaky2(pk_cvt(A1[1][0], A1[1][1]), slope2);
            f[1][1].p[1] = leaky2(pk_cvt(A1[1][2], A1[1][3]), slope2);
            f[1][1].p[2] = leaky2(pk_cvt(A1[3][0], A1[3][1]), slope2);
            f[1][1].p[3] = leaky2(pk_cvt(A1[3][2], A1[3][3]), slope2);
        }

        // ---- output layer: fdot2, then 4-group shuffle reduce ----
#pragma unroll
        for (int c = 0; c < NCHAIN; ++c)
#pragma unroll
            for (int nh = 0; nh < 2; ++nh) {
                float p = 0.0f;
#pragma unroll
                for (int jj = 0; jj < 4; ++jj)
                    p = __builtin_amdgcn_fdot2(f[c][nh].p[jj], wout2[jj], p, false);
                p += __shfl_xor(p, 16, 64);
                p += __shfl_xor(p, 32, 64);   // sum over all 4 k-groups
                float o = p + bo;
                int idx = it * (NCHAIN * 32) + c * 32 + 16 * nh + col;
                // 4 (c,nh) combos, one per 16-lane group (64B coalesced)
                if (g == 2 * c + nh && idx < N) out[idx] = o;
            }

#pragma unroll
        for (int c = 0; c < NCHAIN; ++c) xc2[c] = xn2[c];
    }
}

extern "C" void kernel_launch(void* const* d_in, const int* in_sizes, int n_in,
                              void* d_out, int out_size, void* d_ws, size_t ws_size,
                              hipStream_t stream) {
    const float* x     = (const float*)d_in[0];
    const float* W_in  = (const float*)d_in[1];
    const float* b_in  = (const float*)d_in[2];
    const float* W_hid = (const float*)d_in[3];
    const float* b_hid = (const float*)d_in[4];
    const float* W_out = (const float*)d_in[5];
    const float* b_out = (const float*)d_in[6];
    float* out = (float*)d_out;

    int N = in_sizes[0];
    // 1280 blocks x 4 waves = 5120 waves; ~92-reg waves -> 4-5 waves/SIMD
    // (reg-limited, no longer grid-limited at 2 blocks/CU like R5-R14).
    // LDS 19.5 KiB x 5 blocks/CU = 97.6 KiB ✓. niter = 16384 -> ~3.2
    // iters/wave; per-block weight staging amortized over ~12.8 tiles.
    dim3 block(256);
    dim3 grid(1280);
    mlp_mfma_kernel<<<grid, block, 0, stream>>>(x, W_in, b_in, W_hid, b_hid,
                                                W_out, b_out, out, N);
}